// Round 10
// baseline (331.685 us; speedup 1.0000x reference)
//
#include <hip/hip_runtime.h>

#define NN 100000
#define NE 1200000
#define CH 64
#define NREL 5
#define NCLS 8
#define SLOT 64      // max in-degree tracked; deg ~ Poisson(12), P(>64) ~ 1e-30
#define KTOT 384     // 6*64 (root + 5 relations)
#define HPAD 66      // padded h-stage stride (floats)

typedef _Float16 f16;
typedef _Float16 f16x2 __attribute__((ext_vector_type(2)));
typedef _Float16 f16x4 __attribute__((ext_vector_type(4)));
typedef _Float16 f16x8 __attribute__((ext_vector_type(8)));
typedef float f32x4 __attribute__((ext_vector_type(4)));

#define RFL __builtin_amdgcn_readfirstlane

// ---- x (f32) -> f16 ----
__global__ __launch_bounds__(256) void cvt_f16_kernel(const float* __restrict__ x,
                                                      f16* __restrict__ xh) {
    int t = blockIdx.x * 256 + threadIdx.x;
    if (t >= NN * CH / 4) return;
    float4 v = reinterpret_cast<const float4*>(x)[t];
    f16x4 h = {(f16)v.x, (f16)v.y, (f16)v.z, (f16)v.w};
    *reinterpret_cast<f16x4*>(xh + (size_t)t * 4) = h;
}

// ---- build per-dst edge lists: sorted[d*SLOT+k] = src | (rel<<17) ----
__global__ __launch_bounds__(256) void scatter_kernel(const int* __restrict__ src,
                                                      const int* __restrict__ dst,
                                                      const int* __restrict__ et,
                                                      int* __restrict__ cursor,
                                                      int* __restrict__ sorted) {
    int e = blockIdx.x * 256 + threadIdx.x;
    if (e >= NE) return;
    int d = dst[e];
    int pos = atomicAdd(&cursor[d], 1);
    if (pos < SLOT) sorted[(size_t)d * SLOT + pos] = src[e] | (et[e] << 17);
}

// ---- in-place counting sort of each node's edge list by relation ----
// one wave per node: ballot counts -> prefix offsets -> rank via masked popc
__global__ __launch_bounds__(256, 8) void sort_rel(const int* __restrict__ cursor,
                                                   int* __restrict__ sorted) {
    int wv = threadIdx.x >> 6;
    int node = blockIdx.x * 4 + RFL(wv);
    if (node >= NN) return;
    int lane = threadIdx.x & 63;
    int deg = cursor[node];
    if (deg > SLOT) deg = SLOT;
    int w = sorted[(size_t)node * SLOT + lane];
    uint r = (uint)w >> 17;
    bool valid = lane < deg;
    unsigned long long b0 = __ballot(valid && r == 0);
    unsigned long long b1 = __ballot(valid && r == 1);
    unsigned long long b2 = __ballot(valid && r == 2);
    unsigned long long b3 = __ballot(valid && r == 3);
    unsigned long long b4 = __ballot(valid && r == 4);
    int st1 = (int)__popcll(b0);
    int st2 = st1 + (int)__popcll(b1);
    int st3 = st2 + (int)__popcll(b2);
    int st4 = st3 + (int)__popcll(b3);
    unsigned long long below = (1ull << lane) - 1ull;
    unsigned long long br = (r == 0) ? b0 : (r == 1) ? b1 : (r == 2) ? b2 : (r == 3) ? b3 : b4;
    int str = (r == 0) ? 0 : (r == 1) ? st1 : (r == 2) ? st2 : (r == 3) ? st3 : st4;
    int pos = str + (int)__popcll(br & below);
    // read happened above; same-wave write-after-read is ordered by waitcnt
    if (valid) sorted[(size_t)node * SLOT + pos] = w;
}

// ---- convert weights to f16 B^T layout: Btg[layer][n][k] ----
__global__ __launch_bounds__(256) void prep_weights(const float* __restrict__ root1,
                                                    const float* __restrict__ W1,
                                                    const float* __restrict__ root2,
                                                    const float* __restrict__ W2,
                                                    f16* __restrict__ Btg) {
    int o = blockIdx.x * 256 + threadIdx.x;
    if (o >= 2 * 64 * KTOT) return;
    int layer = o / (64 * KTOT);
    int rem = o % (64 * KTOT);
    int n = rem / KTOT, k = rem % KTOT;
    const float* R = layer ? root2 : root1;
    const float* W = layer ? W2 : W1;
    float v = (k < CH) ? R[k * CH + n] : W[(size_t)(k - CH) * CH + n];
    Btg[o] = (f16)v;
}

// One block = 16 nodes, 256 threads (4 waves), ~12.5 KB LDS -> 8 blocks/CU.
// Phase 1: wave gathers 4 nodes; PAIR-processing: lanes 0-31 = edge A, 32-63 =
//          edge B, uint load (2 f16 ch)/lane, v_pk_add_f16 accumulate; relation-
//          sorted lists make most pairs single-ladder. Halves merged by
//          shfl_xor(32), normalized in f32 at the LDS write.
// Phase 2: wave w computes N-tile w: 12x mfma_16x16x32_f16; A from LDS, B from
//          global (48 KB panel, identical across blocks -> L2-resident).
// Epilogue: relu+f16 store (layer1) or f32 out + fused classifier (layer2).
template<bool CLS>
__global__ __launch_bounds__(256, 8) void fused_layer2(
    const f16* __restrict__ in, const f16* __restrict__ Btg,
    const float* __restrict__ bias,
    const int* __restrict__ cursor, const int* __restrict__ sorted,
    float* __restrict__ outf, f16* __restrict__ outh,
    const float* __restrict__ Wc, const float* __restrict__ bc,
    float* __restrict__ logits) {
    __shared__ __align__(16) char smem[16 * 784];
    f16* Ap = (f16*)smem;

    const int tid = threadIdx.x;
    const int wv = tid >> 6, lane = tid & 63;
    const int wvu = RFL(wv);
    const int ch2 = lane & 31;
    const bool lo32 = lane < 32;
    const int nb0 = blockIdx.x * 16;
    const f16x2 hz2 = {(f16)0.f, (f16)0.f};

#define LADP(RS, HV, INC)                                              \
    if ((RS) == 0)      { A0 += (HV); c0 += (INC); }                   \
    else if ((RS) == 1) { A1 += (HV); c1 += (INC); }                   \
    else if ((RS) == 2) { A2 += (HV); c2 += (INC); }                   \
    else if ((RS) == 3) { A3 += (HV); c3 += (INC); }                   \
    else                { A4 += (HV); c4 += (INC); }

#define PAIR(WA, WB, E0) {                                             \
    int w0 = RFL(WA);                                                  \
    int w1 = RFL(WB);                                                  \
    bool full = ((E0) + 1 < deg);                                      \
    if (!full) w1 = w0;                                                \
    uint r0 = (uint)w0 >> 17, r1 = (uint)w1 >> 17;                     \
    uint b0a = ((uint)w0 & 0x1FFFF) * 128u + (uint)ch2 * 4u;           \
    uint b1a = ((uint)w1 & 0x1FFFF) * 128u + (uint)ch2 * 4u;           \
    uint off = lo32 ? b0a : b1a;                                       \
    uint vv = *(const uint*)((const char*)in + off);                   \
    if (!full) vv = lo32 ? vv : 0u;                                    \
    f16x2 hv = __builtin_bit_cast(f16x2, vv);                          \
    if (r0 == r1) { int inc = full ? 2 : 1; LADP(r0, hv, inc) }        \
    else {                                                             \
        f16x2 hva = lo32 ? hv : hz2;                                   \
        f16x2 hvb = lo32 ? hz2 : hv;                                   \
        LADP(r0, hva, 1)                                               \
        LADP(r1, hvb, 1)                                               \
    }                                                                  \
}

#define MST(AV, SC, M) {                                               \
    int _ai = __builtin_bit_cast(int, AV);                             \
    int _bi = __shfl_xor(_ai, 32);                                     \
    f16x2 _t = AV + __builtin_bit_cast(f16x2, _bi);                    \
    if (lo32) {                                                        \
        f16x2 _o = {(f16)((float)_t.x * (SC)), (f16)((float)_t.y * (SC))}; \
        *(uint*)((char*)arow + (M) * 128 + ch2 * 4) = __builtin_bit_cast(uint, _o); \
    }                                                                  \
}

    // ---- phase 1: gather 4 nodes per wave ----
    for (int q = 0; q < 4; ++q) {
        int nl = wvu * 4 + q;
        int i = nb0 + nl;
        f16* arow = Ap + nl * 392;
        if (i >= NN) {
#pragma unroll
            for (int m = 0; m < 6; ++m) arow[m * 64 + lane] = (f16)0.f;
            continue;
        }
        int deg = cursor[i];
        if (deg > SLOT) deg = SLOT;
        const int* sp = sorted + (size_t)i * SLOT;

        f16 sv = in[(size_t)i * CH + lane];
        f16x2 A0 = hz2, A1 = hz2, A2 = hz2, A3 = hz2, A4 = hz2;
        int c0 = 0, c1 = 0, c2 = 0, c3 = 0, c4 = 0;

        if (deg > 0) {
            int npairs = (deg + 1) >> 1;
            int4 pk = *(const int4*)sp;
            for (int p0 = 0; p0 < npairs; p0 += 2) {
                int4 nx = *(const int4*)(sp + 2 * p0 + 4);  // slack guarantees in-bounds
                PAIR(pk.x, pk.y, 2 * p0)
                if (p0 + 1 < npairs) PAIR(pk.z, pk.w, 2 * p0 + 2)
                pk = nx;
            }
        }

        arow[lane] = sv;  // self row (no relu needed: h1 stored pre-relu'd)
        float s0 = 1.0f / (float)(c0 > 0 ? c0 : 1);
        float s1 = 1.0f / (float)(c1 > 0 ? c1 : 1);
        float s2 = 1.0f / (float)(c2 > 0 ? c2 : 1);
        float s3 = 1.0f / (float)(c3 > 0 ? c3 : 1);
        float s4 = 1.0f / (float)(c4 > 0 ? c4 : 1);
        MST(A0, s0, 1) MST(A1, s1, 2) MST(A2, s2, 3) MST(A3, s3, 4) MST(A4, s4, 5)
    }
#undef PAIR
#undef LADP
#undef MST
    __syncthreads();

    // ---- phase 2: MFMA. wave w -> N-tile w (cols w*16..w*16+15) ----
    const int col = lane & 15, lg = lane >> 4;
    float bv = bias[wvu * 16 + col];
    f32x4 acc = {bv, bv, bv, bv};
    const char* Ab = (const char*)Ap + col * 784 + lg * 16;
    const char* Bb = (const char*)Btg + (size_t)(wvu * 16 + col) * 768 + lg * 16;
#pragma unroll
    for (int k = 0; k < KTOT / 32; ++k) {
        f16x8 af = *(const f16x8*)(Ab + k * 64);
        f16x8 bf = *(const f16x8*)(Bb + k * 64);
        acc = __builtin_amdgcn_mfma_f32_16x16x32_f16(af, bf, acc, 0, 0, 0);
    }

    if (!CLS) {
#pragma unroll
        for (int r = 0; r < 4; ++r) {
            int node = nb0 + lg * 4 + r;
            if (node < NN)
                outh[(size_t)node * CH + wvu * 16 + col] = (f16)fmaxf(acc[r], 0.f);
        }
    } else {
        __syncthreads();  // all Ap reads done -> safe to reuse smem as h-stage
        float* hst = (float*)smem;  // [16][HPAD]
#pragma unroll
        for (int r = 0; r < 4; ++r) {
            int nl = lg * 4 + r;
            int node = nb0 + nl;
            hst[nl * HPAD + wvu * 16 + col] = acc[r];
            if (node < NN)
                outf[(size_t)node * CH + wvu * 16 + col] = acc[r];
        }
        __syncthreads();
        float wcr[NCLS];
#pragma unroll
        for (int c = 0; c < NCLS; ++c) wcr[c] = Wc[lane * NCLS + c];
        for (int q = 0; q < 4; ++q) {
            int nl = wvu * 4 + q;
            int i = nb0 + nl;
            if (i >= NN) continue;
            float v = hst[nl * HPAD + lane];
            float p[NCLS];
#pragma unroll
            for (int c = 0; c < NCLS; ++c) p[c] = v * wcr[c];
#pragma unroll
            for (int off = 32; off > 0; off >>= 1) {
#pragma unroll
                for (int c = 0; c < NCLS; ++c) p[c] += __shfl_xor(p[c], off);
            }
            if (lane == 0) {
                float4 lo = make_float4(p[0] + bc[0], p[1] + bc[1], p[2] + bc[2], p[3] + bc[3]);
                float4 hi = make_float4(p[4] + bc[4], p[5] + bc[5], p[6] + bc[6], p[7] + bc[7]);
                *reinterpret_cast<float4*>(&logits[(size_t)i * NCLS]) = lo;
                *reinterpret_cast<float4*>(&logits[(size_t)i * NCLS + 4]) = hi;
            }
        }
    }
}

extern "C" void kernel_launch(void* const* d_in, const int* in_sizes, int n_in,
                              void* d_out, int out_size, void* d_ws, size_t ws_size,
                              hipStream_t stream) {
    const float* x     = (const float*)d_in[0];
    const int*   ei    = (const int*)d_in[1];
    const int*   et    = (const int*)d_in[2];
    const float* W1    = (const float*)d_in[3];
    const float* root1 = (const float*)d_in[4];
    const float* b1    = (const float*)d_in[5];
    const float* W2    = (const float*)d_in[6];
    const float* root2 = (const float*)d_in[7];
    const float* b2    = (const float*)d_in[8];
    const float* Wc    = (const float*)d_in[9];
    const float* bc    = (const float*)d_in[10];
    const int* src = ei;
    const int* dst = ei + NE;

    float* h2     = (float*)d_out;            // [NN][CH]
    float* logits = h2 + (size_t)NN * CH;     // [NN][NCLS]

    int* cursor = (int*)d_ws;                                   // [NN]
    int* sorted = cursor + NN;                                  // [NN][SLOT] + 16 slack
    f16* h1h    = (f16*)(sorted + (size_t)NN * SLOT + 16);      // [NN][CH]
    f16* xh     = h1h + (size_t)NN * CH;                        // [NN][CH]
    f16* Btg    = xh + (size_t)NN * CH;                         // [2][64][KTOT]

    (void)hipMemsetAsync(cursor, 0, (size_t)NN * 4, stream);
    cvt_f16_kernel<<<(NN * CH / 4 + 255) / 256, 256, 0, stream>>>(x, xh);
    scatter_kernel<<<(NE + 255) / 256, 256, 0, stream>>>(src, dst, et, cursor, sorted);
    sort_rel<<<(NN + 3) / 4, 256, 0, stream>>>(cursor, sorted);
    prep_weights<<<(2 * 64 * KTOT + 255) / 256, 256, 0, stream>>>(root1, W1, root2, W2, Btg);

    int nBlk = (NN + 15) / 16;  // 6250
    fused_layer2<false><<<nBlk, 256, 0, stream>>>(
        xh, Btg, b1, cursor, sorted, nullptr, h1h, nullptr, nullptr, nullptr);
    fused_layer2<true><<<nBlk, 256, 0, stream>>>(
        h1h, Btg + (size_t)64 * KTOT, b2, cursor, sorted, h2, nullptr, Wc, bc, logits);
}

// Round 11
// 304.205 us; speedup vs baseline: 1.0903x; 1.0903x over previous
//
#include <hip/hip_runtime.h>

#define NN 100000
#define NE 1200000
#define CH 64
#define NREL 5
#define NCLS 8
#define SLOT 64      // max in-degree tracked; deg ~ Poisson(12), P(>64) ~ 1e-30
#define KTOT 384     // 6*64 (root + 5 relations)
#define HPAD 66      // padded h-stage stride (floats)

typedef _Float16 f16;
typedef _Float16 f16x2 __attribute__((ext_vector_type(2)));
typedef _Float16 f16x4 __attribute__((ext_vector_type(4)));
typedef _Float16 f16x8 __attribute__((ext_vector_type(8)));
typedef float f32x4 __attribute__((ext_vector_type(4)));

#define RFL __builtin_amdgcn_readfirstlane

// ---- fused: blocks [0,cvtB) convert x->f16; blocks [cvtB,..) scatter edges ----
__global__ __launch_bounds__(256) void cvt_scatter_kernel(
    const float* __restrict__ x, f16* __restrict__ xh,
    const int* __restrict__ src, const int* __restrict__ dst,
    const int* __restrict__ et, int* __restrict__ cursor,
    int* __restrict__ sorted, int cvtB) {
    if ((int)blockIdx.x < cvtB) {
        int t = blockIdx.x * 256 + threadIdx.x;
        if (t >= NN * CH / 4) return;
        float4 v = reinterpret_cast<const float4*>(x)[t];
        f16x4 h = {(f16)v.x, (f16)v.y, (f16)v.z, (f16)v.w};
        *reinterpret_cast<f16x4*>(xh + (size_t)t * 4) = h;
    } else {
        int e = (blockIdx.x - cvtB) * 256 + threadIdx.x;
        if (e >= NE) return;
        int d = dst[e];
        int pos = atomicAdd(&cursor[d], 1);
        if (pos < SLOT) sorted[(size_t)d * SLOT + pos] = src[e] | (et[e] << 17);
    }
}

// ---- in-place counting sort of each node's edge list by relation ----
__global__ __launch_bounds__(256, 8) void sort_rel(const int* __restrict__ cursor,
                                                   int* __restrict__ sorted) {
    int wv = threadIdx.x >> 6;
    int node = blockIdx.x * 4 + RFL(wv);
    if (node >= NN) return;
    int lane = threadIdx.x & 63;
    int deg = cursor[node];
    if (deg > SLOT) deg = SLOT;
    int w = sorted[(size_t)node * SLOT + lane];
    uint r = (uint)w >> 17;
    bool valid = lane < deg;
    unsigned long long b0 = __ballot(valid && r == 0);
    unsigned long long b1 = __ballot(valid && r == 1);
    unsigned long long b2 = __ballot(valid && r == 2);
    unsigned long long b3 = __ballot(valid && r == 3);
    unsigned long long b4 = __ballot(valid && r == 4);
    int st1 = (int)__popcll(b0);
    int st2 = st1 + (int)__popcll(b1);
    int st3 = st2 + (int)__popcll(b2);
    int st4 = st3 + (int)__popcll(b3);
    unsigned long long below = (1ull << lane) - 1ull;
    unsigned long long br = (r == 0) ? b0 : (r == 1) ? b1 : (r == 2) ? b2 : (r == 3) ? b3 : b4;
    int str = (r == 0) ? 0 : (r == 1) ? st1 : (r == 2) ? st2 : (r == 3) ? st3 : st4;
    int pos = str + (int)__popcll(br & below);
    if (valid) sorted[(size_t)node * SLOT + pos] = w;
}

// ---- convert weights to f16 B^T layout: Btg[layer][n][k] ----
__global__ __launch_bounds__(256) void prep_weights(const float* __restrict__ root1,
                                                    const float* __restrict__ W1,
                                                    const float* __restrict__ root2,
                                                    const float* __restrict__ W2,
                                                    f16* __restrict__ Btg) {
    int o = blockIdx.x * 256 + threadIdx.x;
    if (o >= 2 * 64 * KTOT) return;
    int layer = o / (64 * KTOT);
    int rem = o % (64 * KTOT);
    int n = rem / KTOT, k = rem % KTOT;
    const float* R = layer ? root2 : root1;
    const float* W = layer ? W2 : W1;
    float v = (k < CH) ? R[k * CH + n] : W[(size_t)(k - CH) * CH + n];
    Btg[o] = (f16)v;
}

// One block = 16 nodes, 256 threads (4 waves), ~12.5 KB LDS -> 8 blocks/CU.
// Phase 1 edge loop: 8 edges/iter as 4 pair-loads — all 4 addresses computed and
//   all 4 uint loads ISSUED before any ladder consumes them (R9's MLP) while
//   keeping R10's 2-edges-per-instruction pk-f16 accumulation (halved VALU).
// Phase 2: wave w computes N-tile w: 12x mfma_16x16x32_f16; A from LDS, B from
//   global (48 KB panel, L2-resident across all blocks).
template<bool CLS>
__global__ __launch_bounds__(256, 8) void fused_layer2(
    const f16* __restrict__ in, const f16* __restrict__ Btg,
    const float* __restrict__ bias,
    const int* __restrict__ cursor, const int* __restrict__ sorted,
    float* __restrict__ outf, f16* __restrict__ outh,
    const float* __restrict__ Wc, const float* __restrict__ bc,
    float* __restrict__ logits) {
    __shared__ __align__(16) char smem[16 * 784];
    f16* Ap = (f16*)smem;

    const int tid = threadIdx.x;
    const int wv = tid >> 6, lane = tid & 63;
    const int wvu = RFL(wv);
    const int ch2 = lane & 31;
    const bool lo32 = lane < 32;
    const uint choff = (uint)ch2 * 4u;
    const int nb0 = blockIdx.x * 16;
    const f16x2 hz2 = {(f16)0.f, (f16)0.f};

#define SBASE(W) ({ uint _s = (uint)(W) & 0x1FFFFu; _s = _s < (uint)NN ? _s : 0u; _s * 128u; })

#define LADP(RS, HV, INC)                                              \
    if ((RS) == 0)      { A0 += (HV); c0 += (INC); }                   \
    else if ((RS) == 1) { A1 += (HV); c1 += (INC); }                   \
    else if ((RS) == 2) { A2 += (HV); c2 += (INC); }                   \
    else if ((RS) == 3) { A3 += (HV); c3 += (INC); }                   \
    else                { A4 += (HV); c4 += (INC); }

// accumulate one pair: wa/wb scalar edge words, full = both edges valid
#define PACC(WA, WB, FULL, VV) {                                       \
    uint _r0 = (uint)(WA) >> 17, _r1 = (uint)(WB) >> 17;               \
    uint _v = (VV);                                                    \
    if (!(FULL)) _v = lo32 ? _v : 0u;                                  \
    f16x2 _hv = __builtin_bit_cast(f16x2, _v);                         \
    if (_r0 == _r1) { int _inc = (FULL) ? 2 : 1; LADP(_r0, _hv, _inc) }\
    else {                                                             \
        f16x2 _ha = lo32 ? _hv : hz2;                                  \
        f16x2 _hb = lo32 ? hz2 : _hv;                                  \
        LADP(_r0, _ha, 1)                                              \
        LADP(_r1, _hb, 1)                                              \
    }                                                                  \
}

#define MST(AV, SC, M) {                                               \
    int _ai = __builtin_bit_cast(int, AV);                             \
    int _bi = __shfl_xor(_ai, 32);                                     \
    f16x2 _t = AV + __builtin_bit_cast(f16x2, _bi);                    \
    if (lo32) {                                                        \
        f16x2 _o = {(f16)((float)_t.x * (SC)), (f16)((float)_t.y * (SC))}; \
        *(uint*)((char*)arow + (M) * 128 + ch2 * 4) = __builtin_bit_cast(uint, _o); \
    }                                                                  \
}

    // ---- phase 1: gather 4 nodes per wave ----
    for (int q = 0; q < 4; ++q) {
        int nl = wvu * 4 + q;
        int i = nb0 + nl;
        f16* arow = Ap + nl * 392;
        if (i >= NN) {
#pragma unroll
            for (int m = 0; m < 6; ++m) arow[m * 64 + lane] = (f16)0.f;
            continue;
        }
        int deg = cursor[i];
        if (deg > SLOT) deg = SLOT;
        const int* sp = sorted + (size_t)i * SLOT;

        f16 sv = in[(size_t)i * CH + lane];
        f16x2 A0 = hz2, A1 = hz2, A2 = hz2, A3 = hz2, A4 = hz2;
        int c0 = 0, c1 = 0, c2 = 0, c3 = 0, c4 = 0;

        if (deg > 0) {
            int npairs = (deg + 1) >> 1;
            int4 pk  = *(const int4*)sp;
            int4 pk2 = *(const int4*)(sp + 4);
            for (int p0 = 0; p0 < npairs; p0 += 4) {
                // prefetch next 8 edge words (16-int slack guarantees in-bounds)
                int4 nx  = *(const int4*)(sp + 2 * p0 + 8);
                int4 nx2 = *(const int4*)(sp + 2 * p0 + 12);
                // extract all 8 words to SGPRs
                int w0a = RFL(pk.x),  w0b = RFL(pk.y);
                int w1a = RFL(pk.z),  w1b = RFL(pk.w);
                int w2a = RFL(pk2.x), w2b = RFL(pk2.y);
                int w3a = RFL(pk2.z), w3b = RFL(pk2.w);
                bool f0 = 2 * p0 + 1 < deg;
                bool v1 = p0 + 1 < npairs, f1 = 2 * p0 + 3 < deg;
                bool v2 = p0 + 2 < npairs, f2 = 2 * p0 + 5 < deg;
                bool v3 = p0 + 3 < npairs, f3 = 2 * p0 + 7 < deg;
                if (!f0) w0b = w0a;
                if (!f1) w1b = w1a;
                if (!f2) w2b = w2a;
                if (!f3) w3b = w3a;
                // compute all 4 per-lane offsets (scalar bases, clamped)
                uint off0 = (lo32 ? SBASE(w0a) : SBASE(w0b)) + choff;
                uint off1 = (lo32 ? SBASE(w1a) : SBASE(w1b)) + choff;
                uint off2 = (lo32 ? SBASE(w2a) : SBASE(w2b)) + choff;
                uint off3 = (lo32 ? SBASE(w3a) : SBASE(w3b)) + choff;
                // issue all 4 loads before any ladder (MLP = 4)
                uint vv0 = *(const uint*)((const char*)in + off0);
                uint vv1 = *(const uint*)((const char*)in + off1);
                uint vv2 = *(const uint*)((const char*)in + off2);
                uint vv3 = *(const uint*)((const char*)in + off3);
                // accumulate
                PACC(w0a, w0b, f0, vv0)
                if (v1) PACC(w1a, w1b, f1, vv1)
                if (v2) PACC(w2a, w2b, f2, vv2)
                if (v3) PACC(w3a, w3b, f3, vv3)
                pk = nx; pk2 = nx2;
            }
        }

        arow[lane] = sv;  // self row (pre-activation input already applied upstream)
        float s0 = 1.0f / (float)(c0 > 0 ? c0 : 1);
        float s1 = 1.0f / (float)(c1 > 0 ? c1 : 1);
        float s2 = 1.0f / (float)(c2 > 0 ? c2 : 1);
        float s3 = 1.0f / (float)(c3 > 0 ? c3 : 1);
        float s4 = 1.0f / (float)(c4 > 0 ? c4 : 1);
        MST(A0, s0, 1) MST(A1, s1, 2) MST(A2, s2, 3) MST(A3, s3, 4) MST(A4, s4, 5)
    }
#undef PACC
#undef LADP
#undef MST
#undef SBASE
    __syncthreads();

    // ---- phase 2: MFMA. wave w -> N-tile w (cols w*16..w*16+15) ----
    const int col = lane & 15, lg = lane >> 4;
    float bv = bias[wvu * 16 + col];
    f32x4 acc = {bv, bv, bv, bv};
    const char* Ab = (const char*)Ap + col * 784 + lg * 16;
    const char* Bb = (const char*)Btg + (size_t)(wvu * 16 + col) * 768 + lg * 16;
#pragma unroll
    for (int k = 0; k < KTOT / 32; ++k) {
        f16x8 af = *(const f16x8*)(Ab + k * 64);
        f16x8 bf = *(const f16x8*)(Bb + k * 64);
        acc = __builtin_amdgcn_mfma_f32_16x16x32_f16(af, bf, acc, 0, 0, 0);
    }

    if (!CLS) {
#pragma unroll
        for (int r = 0; r < 4; ++r) {
            int node = nb0 + lg * 4 + r;
            if (node < NN)
                outh[(size_t)node * CH + wvu * 16 + col] = (f16)fmaxf(acc[r], 0.f);
        }
    } else {
        __syncthreads();  // all Ap reads done -> reuse smem as h-stage
        float* hst = (float*)smem;  // [16][HPAD]
#pragma unroll
        for (int r = 0; r < 4; ++r) {
            int nl = lg * 4 + r;
            int node = nb0 + nl;
            hst[nl * HPAD + wvu * 16 + col] = acc[r];
            if (node < NN)
                outf[(size_t)node * CH + wvu * 16 + col] = acc[r];
        }
        __syncthreads();
        float wcr[NCLS];
#pragma unroll
        for (int c = 0; c < NCLS; ++c) wcr[c] = Wc[lane * NCLS + c];
        for (int q = 0; q < 4; ++q) {
            int nl = wvu * 4 + q;
            int i = nb0 + nl;
            if (i >= NN) continue;
            float v = hst[nl * HPAD + lane];
            float p[NCLS];
#pragma unroll
            for (int c = 0; c < NCLS; ++c) p[c] = v * wcr[c];
#pragma unroll
            for (int off = 32; off > 0; off >>= 1) {
#pragma unroll
                for (int c = 0; c < NCLS; ++c) p[c] += __shfl_xor(p[c], off);
            }
            if (lane == 0) {
                float4 lo = make_float4(p[0] + bc[0], p[1] + bc[1], p[2] + bc[2], p[3] + bc[3]);
                float4 hi = make_float4(p[4] + bc[4], p[5] + bc[5], p[6] + bc[6], p[7] + bc[7]);
                *reinterpret_cast<float4*>(&logits[(size_t)i * NCLS]) = lo;
                *reinterpret_cast<float4*>(&logits[(size_t)i * NCLS + 4]) = hi;
            }
        }
    }
}

extern "C" void kernel_launch(void* const* d_in, const int* in_sizes, int n_in,
                              void* d_out, int out_size, void* d_ws, size_t ws_size,
                              hipStream_t stream) {
    const float* x     = (const float*)d_in[0];
    const int*   ei    = (const int*)d_in[1];
    const int*   et    = (const int*)d_in[2];
    const float* W1    = (const float*)d_in[3];
    const float* root1 = (const float*)d_in[4];
    const float* b1    = (const float*)d_in[5];
    const float* W2    = (const float*)d_in[6];
    const float* root2 = (const float*)d_in[7];
    const float* b2    = (const float*)d_in[8];
    const float* Wc    = (const float*)d_in[9];
    const float* bc    = (const float*)d_in[10];
    const int* src = ei;
    const int* dst = ei + NE;

    float* h2     = (float*)d_out;            // [NN][CH]
    float* logits = h2 + (size_t)NN * CH;     // [NN][NCLS]

    int* cursor = (int*)d_ws;                                   // [NN]
    int* sorted = cursor + NN;                                  // [NN][SLOT] + 16 slack
    f16* h1h    = (f16*)(sorted + (size_t)NN * SLOT + 16);      // [NN][CH]
    f16* xh     = h1h + (size_t)NN * CH;                        // [NN][CH]
    f16* Btg    = xh + (size_t)NN * CH;                         // [2][64][KTOT]

    (void)hipMemsetAsync(cursor, 0, (size_t)NN * 4, stream);
    int cvtB = (NN * CH / 4 + 255) / 256;
    int sctB = (NE + 255) / 256;
    cvt_scatter_kernel<<<cvtB + sctB, 256, 0, stream>>>(x, xh, src, dst, et, cursor, sorted, cvtB);
    sort_rel<<<(NN + 3) / 4, 256, 0, stream>>>(cursor, sorted);
    prep_weights<<<(2 * 64 * KTOT + 255) / 256, 256, 0, stream>>>(root1, W1, root2, W2, Btg);

    int nBlk = (NN + 15) / 16;  // 6250
    fused_layer2<false><<<nBlk, 256, 0, stream>>>(
        xh, Btg, b1, cursor, sorted, nullptr, h1h, nullptr, nullptr, nullptr);
    fused_layer2<true><<<nBlk, 256, 0, stream>>>(
        h1h, Btg + (size_t)64 * KTOT, b2, cursor, sorted, h2, nullptr, Wc, bc, logits);
}